// Round 12
// baseline (335.160 us; speedup 1.0000x reference)
//
#include <hip/hip_runtime.h>
#include <hip/hip_bf16.h>

#define N_NODES 50000
#define HEADS 4
#define DHEAD 32
#define F 128           // HEADS*DHEAD = in/out feature width everywhere
#define NEG_SLOPE 0.2f

typedef unsigned int uint;
typedef unsigned short ushort;
typedef __attribute__((ext_vector_type(8))) short bf16x8;
typedef __attribute__((ext_vector_type(4))) float f32x4;

__device__ __forceinline__ float bf2f(ushort u) {
    union { uint i; float f; } c; c.i = ((uint)u) << 16; return c.f;
}
__device__ __forceinline__ ushort f2bf(float f) {
    union { float f; uint i; } c; c.f = f;
    uint u = c.i + 0x7FFF + ((c.i >> 16) & 1);   // round-to-nearest-even
    return (ushort)(u >> 16);
}

// ---------------------------------------------------------------------------
// CSR build: rank+hist -> scan (+ counting-sort perm, LDS atomics only) ->
// posfix -> range-split scatter
// ---------------------------------------------------------------------------
__global__ void rank_hist_kernel(const int* __restrict__ dst, int* __restrict__ counts,
                                 int* __restrict__ rank, int E) {
    int i = blockIdx.x * 256 + threadIdx.x;
    if (i < E) rank[i] = atomicAdd(&counts[dst[i]], 1);
}

__global__ __launch_bounds__(256) void scanA_kernel(const int* __restrict__ counts,
                                                    int* __restrict__ local_sc,
                                                    int* __restrict__ partials,
                                                    int* __restrict__ blockbin,
                                                    int N, int NB) {
    __shared__ int lbin[64];
    int tid = threadIdx.x;
    if (tid < 64) lbin[tid] = 0;
    __syncthreads();
    int i = blockIdx.x * 256 + tid;
    int v = (i < N) ? counts[i] : 0;
    if (i < N) atomicAdd(&lbin[v < 63 ? v : 63], 1);
    int lane = tid & 63;
    int w = tid >> 6;
    int x = v;
#pragma unroll
    for (int off = 1; off < 64; off <<= 1) {
        int t = __shfl_up(x, off);
        if (lane >= off) x += t;
    }
    __shared__ int wsum[4];
    if (lane == 63) wsum[w] = x;
    __syncthreads();
    int wpre = 0;
#pragma unroll
    for (int k = 0; k < 4; k++)
        if (k < w) wpre += wsum[k];
    if (i < N) local_sc[i] = x - v + wpre;
    if (tid == 255) partials[blockIdx.x] = wpre + x;
    __syncthreads();
    if (tid < 64) blockbin[tid * NB + blockIdx.x] = lbin[tid];   // bin-major
}

__global__ __launch_bounds__(256) void scanB_kernel(int* __restrict__ partials, int NP,
                                                    int* __restrict__ blockbin, int M) {
    int tid = threadIdx.x;
    int lane = tid & 63;
    int w = tid >> 6;
    __shared__ int wsum[4];
    {
        int v = (tid < NP) ? partials[tid] : 0;
        int x = v;
#pragma unroll
        for (int off = 1; off < 64; off <<= 1) {
            int t = __shfl_up(x, off);
            if (lane >= off) x += t;
        }
        if (lane == 63) wsum[w] = x;
        __syncthreads();
        int wpre = 0;
#pragma unroll
        for (int k = 0; k < 4; k++)
            if (k < w) wpre += wsum[k];
        if (tid < NP) partials[tid] = x - v + wpre;
        __syncthreads();
    }
    {
        int chunk = (M + 255) / 256;
        int lo = tid * chunk;
        int hi = lo + chunk; if (hi > M) hi = M; if (lo > M) lo = M;
        int sum = 0;
        for (int i = lo; i < hi; i++) sum += blockbin[i];
        int x = sum;
#pragma unroll
        for (int off = 1; off < 64; off <<= 1) {
            int t = __shfl_up(x, off);
            if (lane >= off) x += t;
        }
        if (lane == 63) wsum[w] = x;
        __syncthreads();
        int wpre = 0;
#pragma unroll
        for (int k = 0; k < 4; k++)
            if (k < w) wpre += wsum[k];
        int pre = x - sum + wpre;
        for (int i = lo; i < hi; i++) {
            int c = blockbin[i];
            blockbin[i] = pre;
            pre += c;
        }
    }
}

__global__ __launch_bounds__(256) void scanC_kernel(int* __restrict__ offs,
                                                    const int* __restrict__ partials,
                                                    const int* __restrict__ counts,
                                                    const int* __restrict__ blockbin,
                                                    int* __restrict__ perm,
                                                    int N, int E, int NB) {
    __shared__ int lcur[64];
    int tid = threadIdx.x;
    if (tid < 64) lcur[tid] = blockbin[tid * NB + blockIdx.x];
    __syncthreads();
    int i = blockIdx.x * 256 + tid;
    if (i < N) {
        offs[i] += partials[blockIdx.x];
        int d = counts[i];
        int pos = atomicAdd(&lcur[d < 63 ? d : 63], 1);
        perm[pos] = i;
    }
    if (i == 0) offs[N] = E;
}

__global__ void posfix_kernel(const int* __restrict__ dst, const int* __restrict__ offs,
                              int* __restrict__ rank, int E) {
    int i = blockIdx.x * 256 + threadIdx.x;
    if (i < E) rank[i] += offs[dst[i]];
}

#define SCH 2048   // edges per block chunk
__global__ __launch_bounds__(256) void scatter_ranged_kernel(
    const int* __restrict__ src, const int* __restrict__ pos,
    int* __restrict__ csr_src, int E) {
    int range = blockIdx.x & 7;
    int chunk = blockIdx.x >> 3;
    int base = chunk * SCH + threadIdx.x;
    int lo = (int)(((long long)range * E) >> 3);
    int hi = (int)(((long long)(range + 1) * E) >> 3);
#pragma unroll
    for (int k = 0; k < SCH / 256; k++) {
        int i = base + k * 256;
        if (i < E) {
            int p = pos[i];
            if (p >= lo && p < hi) csr_src[p] = src[i];
        }
    }
}

// ---------------------------------------------------------------------------
// Weight transpose + bf16 convert. Blocks 0-2: WT[n][k]=bf16(W[k][n]).
// Blocks 3-4: W-PROJECTED ALR tables (16x128):
//   ALR[c][k] = sum_d W[k][h*32+d] * a[h][d],  h=c&3, a=al (c<4) / ar (4..7).
// ---------------------------------------------------------------------------
__global__ __launch_bounds__(256) void wtrans_kernel(
    const float* __restrict__ W1, const float* __restrict__ W2,
    const float* __restrict__ Wp,
    const float* __restrict__ al1, const float* __restrict__ ar1,
    const float* __restrict__ al2, const float* __restrict__ ar2,
    ushort* __restrict__ WT) {
    if (blockIdx.x < 3) {
        const float* W = (blockIdx.x == 0) ? W1 : (blockIdx.x == 1) ? W2 : Wp;
        ushort* T = WT + (size_t)blockIdx.x * 128 * 128;
        for (int i = threadIdx.x; i < 128 * 128; i += 256) {
            int r = i >> 7, c = i & 127;
            T[c * 128 + r] = f2bf(W[i]);
        }
    } else {
        const float* W   = (blockIdx.x == 3) ? W1 : W2;
        const float* a_l = (blockIdx.x == 3) ? al1 : al2;
        const float* a_r = (blockIdx.x == 3) ? ar1 : ar2;
        ushort* T = WT + 3 * 128 * 128 + (blockIdx.x - 3) * 16 * 128;
        for (int i = threadIdx.x; i < 16 * 128; i += 256) {
            int c = i >> 7, k = i & 127;
            float v = 0.f;
            if (c < 8) {
                int h = c & 3;
                const float* a  = (c < 4) ? (a_l + h * 32) : (a_r + h * 32);
                const float* wr = W + k * 128 + h * 32;
#pragma unroll
                for (int d = 0; d < 32; d++) v += wr[d] * a[d];
            }
            T[i] = f2bf(v);
        }
    }
}

// ---------------------------------------------------------------------------
// MFMA GEMM: C[M,128] = A[M,128] @ B[128,128], B transposed bf16 (BT[n][k]).
// Block = 4 waves, each wave 16 rows x 128 cols.
// ELER: one extra 16x16x32 MFMA chain vs the W-projected ALR table computes
// el (cols 0-3) and er (cols 4-7) for the wave's 16 rows.
// ---------------------------------------------------------------------------
template <bool A_FP32, bool OUT_BF16, bool BIAS, bool ELER>
__global__ __launch_bounds__(256) void mfma_gemm_kernel(
    const void* __restrict__ Av, const ushort* __restrict__ BT,
    const float* __restrict__ bias, const ushort* __restrict__ ALR,
    void* __restrict__ Cv, float* __restrict__ el, float* __restrict__ er, int M) {
    int wid = threadIdx.x >> 6;
    int lane = threadIdx.x & 63;
    int row0 = blockIdx.x * 64 + wid * 16;
    int rsub = lane & 15;
    int kg = lane >> 4;
    int row = row0 + rsub;
    int rowc = (row < M) ? row : (M - 1);

    bf16x8 af[4];
    if (A_FP32) {
        const float* A = (const float*)Av;
        const float* ap = A + (size_t)rowc * 128 + kg * 8;
#pragma unroll
        for (int ks = 0; ks < 4; ks++) {
            float4 lo = *(const float4*)(ap + ks * 32);
            float4 hi = *(const float4*)(ap + ks * 32 + 4);
            bf16x8 v;
            v[0] = (short)f2bf(lo.x); v[1] = (short)f2bf(lo.y);
            v[2] = (short)f2bf(lo.z); v[3] = (short)f2bf(lo.w);
            v[4] = (short)f2bf(hi.x); v[5] = (short)f2bf(hi.y);
            v[6] = (short)f2bf(hi.z); v[7] = (short)f2bf(hi.w);
            af[ks] = v;
        }
    } else {
        const ushort* A = (const ushort*)Av;
        const ushort* ap = A + (size_t)rowc * 128 + kg * 8;
#pragma unroll
        for (int ks = 0; ks < 4; ks++) af[ks] = *(const bf16x8*)(ap + ks * 32);
    }

    f32x4 acc[8];
#pragma unroll
    for (int ct = 0; ct < 8; ct++) acc[ct] = (f32x4){0.f, 0.f, 0.f, 0.f};

    const ushort* bp = BT + (size_t)rsub * 128 + kg * 8;
#pragma unroll
    for (int ks = 0; ks < 4; ks++) {
#pragma unroll
        for (int ct = 0; ct < 8; ct++) {
            bf16x8 bf = *(const bf16x8*)(bp + (size_t)ct * 16 * 128 + ks * 32);
            acc[ct] = __builtin_amdgcn_mfma_f32_16x16x32_bf16(af[ks], bf, acc[ct], 0, 0, 0);
        }
    }

    f32x4 acce = (f32x4){0.f, 0.f, 0.f, 0.f};
    if (ELER) {
        const ushort* ep = ALR + rsub * 128 + kg * 8;
#pragma unroll
        for (int ks = 0; ks < 4; ks++) {
            bf16x8 eb = *(const bf16x8*)(ep + ks * 32);
            acce = __builtin_amdgcn_mfma_f32_16x16x32_bf16(af[ks], eb, acce, 0, 0, 0);
        }
    }

    if (row0 >= M) return;

#pragma unroll
    for (int ct = 0; ct < 8; ct++) {
        int col = ct * 16 + rsub;
        float bv = BIAS ? bias[col] : 0.f;
#pragma unroll
        for (int r = 0; r < 4; r++) {
            int gr = row0 + kg * 4 + r;
            if (gr < M) {
                float v = acc[ct][r] + bv;
                if (OUT_BF16) ((ushort*)Cv)[(size_t)gr * 128 + col] = f2bf(v);
                else          ((float*)Cv)[(size_t)gr * 128 + col] = v;
            }
        }
    }

    if (ELER && rsub < 8) {
#pragma unroll
        for (int r = 0; r < 4; r++) {
            int gr = row0 + kg * 4 + r;
            if (gr < M) {
                if (rsub < 4) el[(size_t)gr * 4 + rsub] = acce[r];
                else          er[(size_t)gr * 4 + (rsub - 4)] = acce[r];
            }
        }
    }
}

// ---------------------------------------------------------------------------
// Head-split aggregate: head = blockIdx.x & 3, so under round-robin
// block->XCD dispatch each XCD touches only one head's 32-column featb slice
// (50000 x 64B = 3.2MB -> L2-resident). 16 lanes per (node, head); lane owns
// 2 columns. Pass1: 1-value online softmax + 4-step reduce. Pass2: 16-edge
// batches (1 el-load + 1 exp per lane per batch), fully-unrolled 16-iter
// inner loop = 16 independent 4B gathers in flight.
// ---------------------------------------------------------------------------
template <bool F32OUT>
__global__ __launch_bounds__(256) void aggregate_head_kernel(
    const ushort* __restrict__ featb, const float* __restrict__ el,
    const float* __restrict__ er, const float* __restrict__ bias,
    const int* __restrict__ offsets, const int* __restrict__ csr_src,
    const int* __restrict__ perm, void* __restrict__ outv, int N) {
    int tid = threadIdx.x;
    int gl = tid & 15;
    int h = blockIdx.x & 3;
    int slot = (blockIdx.x >> 2) * 16 + (tid >> 4);
    if (slot >= N) return;
    int n = perm[slot];
    int start = offsets[n], end = offsets[n + 1];
    float erh = er[(size_t)n * 4 + h];

    // pass 1: online softmax (this head only)
    float m = -1e30f, s = 0.f;
    for (int e = start + gl; e < end; e += 16) {
        int sv = csr_src[e];
        float v = el[(size_t)sv * 4 + h] + erh;
        v = (v >= 0.f) ? v : NEG_SLOPE * v;
        float mn = fmaxf(m, v);
        s = s * __expf(m - mn) + __expf(v - mn);
        m = mn;
    }
#pragma unroll
    for (int off = 1; off < 16; off <<= 1) {
        float mo = __shfl_xor(m, off);
        float so = __shfl_xor(s, off);
        float mn = fmaxf(m, mo);
        s = s * __expf(m - mn) + so * __expf(mo - mn);
        m = mn;
    }
    float rz = (end > start) ? 1.0f / s : 0.f;

    int c0 = h * 32 + gl * 2;         // my 2 columns
    int gbase = (tid & 63) & 48;      // wave-lane base of my 16-lane group
    float acc0 = 0.f, acc1 = 0.f;

    int eb = start;
    for (; eb + 16 <= end; eb += 16) {
        int svj = csr_src[eb + gl];
        float v = el[(size_t)svj * 4 + h] + erh;
        v = (v >= 0.f) ? v : NEG_SLOPE * v;
        float a = __expf(v - m) * rz;
#pragma unroll
        for (int jj = 0; jj < 16; jj++) {
            float ajj = __shfl(a, gbase | jj);
            int svjj  = __shfl(svj, gbase | jj);
            uint f = *(const uint*)(featb + (size_t)svjj * 128 + c0);
            acc0 = fmaf(ajj, bf2f(f & 0xFFFF), acc0);
            acc1 = fmaf(ajj, bf2f(f >> 16), acc1);
        }
    }
    int rem = end - eb;
    if (rem > 0) {
        int ej = eb + ((gl < rem) ? gl : 0);
        int svj = csr_src[ej];
        float v = el[(size_t)svj * 4 + h] + erh;
        v = (v >= 0.f) ? v : NEG_SLOPE * v;
        float a = __expf(v - m) * rz;
        if (gl >= rem) a = 0.f;
        for (int jj = 0; jj < rem; jj++) {
            float ajj = __shfl(a, gbase | jj);
            int svjj  = __shfl(svj, gbase | jj);
            uint f = *(const uint*)(featb + (size_t)svjj * 128 + c0);
            acc0 = fmaf(ajj, bf2f(f & 0xFFFF), acc0);
            acc1 = fmaf(ajj, bf2f(f >> 16), acc1);
        }
    }

    float o0 = acc0 + bias[c0];
    float o1 = acc1 + bias[c0 + 1];
    if (F32OUT) {
        float2 w; w.x = o0; w.y = o1;
        *(float2*)((float*)outv + (size_t)n * 128 + c0) = w;
    } else {
        uint p = (uint)f2bf(o0) | ((uint)f2bf(o1) << 16);
        *(uint*)((ushort*)outv + (size_t)n * 128 + c0) = p;
    }
}

// ---------------------------------------------------------------------------
extern "C" void kernel_launch(void* const* d_in, const int* in_sizes, int n_in,
                              void* d_out, int out_size, void* d_ws, size_t ws_size,
                              hipStream_t stream) {
    const float* x   = (const float*)d_in[0];
    const int*   src = (const int*)d_in[1];
    const int*   dst = (const int*)d_in[2];
    const float* W1  = (const float*)d_in[3];
    const float* al1 = (const float*)d_in[4];
    const float* ar1 = (const float*)d_in[5];
    const float* b1  = (const float*)d_in[6];
    const float* W2  = (const float*)d_in[7];
    const float* al2 = (const float*)d_in[8];
    const float* ar2 = (const float*)d_in[9];
    const float* b2  = (const float*)d_in[10];
    const float* Wp  = (const float*)d_in[11];
    const float* bp  = (const float*)d_in[12];

    const int N = in_sizes[0] / F;      // 50000
    const int E = in_sizes[1];          // 800000

    float* h_out = (float*)d_out;               // [N,128]  (layer-2 output h, checked)
    float* p_out = h_out + (size_t)N * F;       // [N,128]  (projection output, checked)

    const int NB = (N + 255) / 256;     // 196
    const int EB = (E + 255) / 256;

    // workspace carve
    char* w = (char*)d_ws;
    ushort* featb   = (ushort*)w;                               // N*128 bf16
    ushort* h1b     = featb + (size_t)N * F;                    // N*128 bf16
    float* el       = (float*)(h1b + (size_t)N * F);            // N*4
    float* er       = el + (size_t)N * 4;                       // N*4
    int*   offs     = (int*)(er + (size_t)N * 4);               // N+1
    int*   counts   = offs + (N + 1);                           // N
    int*   perm     = counts + N;                               // N
    int*   blockbin = perm + N;                                 // 64*NB
    int*   rank     = blockbin + 64 * NB;                       // E (becomes pos)
    int*   csrsrc   = rank + E;                                 // E
    int*   partials = csrsrc + E;                               // 256
    ushort* WT      = (ushort*)(partials + 256);                // 3*16384 + 2*2048

    // --- CSR build (dst is identical for both layers) ---
    hipMemsetAsync(counts, 0, (size_t)N * 4, stream);
    rank_hist_kernel<<<EB, 256, 0, stream>>>(dst, counts, rank, E);
    scanA_kernel<<<NB, 256, 0, stream>>>(counts, offs, partials, blockbin, N, NB);
    scanB_kernel<<<1, 256, 0, stream>>>(partials, NB, blockbin, 64 * NB);
    scanC_kernel<<<NB, 256, 0, stream>>>(offs, partials, counts, blockbin, perm, N, E, NB);
    posfix_kernel<<<EB, 256, 0, stream>>>(dst, offs, rank, E);
    scatter_ranged_kernel<<<8 * ((E + SCH - 1) / SCH), 256, 0, stream>>>(src, rank, csrsrc, E);

    // --- weight transposes + W-projected ALR tables (bf16) ---
    wtrans_kernel<<<5, 256, 0, stream>>>(W1, W2, Wp, al1, ar1, al2, ar2, WT);
    ushort* WT1  = WT;
    ushort* WT2  = WT + 128 * 128;
    ushort* WTp  = WT + 2 * 128 * 128;
    ushort* ALR1 = WT + 3 * 128 * 128;
    ushort* ALR2 = ALR1 + 16 * 128;

    int ggrid = (N + 63) / 64;
    int agrid = 4 * ((N + 15) / 16);    // 4 head-groups x node chunks

    // --- layer 1 (GEMM + MFMA el/er) ---
    mfma_gemm_kernel<true, true, false, true><<<ggrid, 256, 0, stream>>>(
        x, WT1, nullptr, ALR1, featb, el, er, N);
    aggregate_head_kernel<false><<<agrid, 256, 0, stream>>>(
        featb, el, er, b1, offs, csrsrc, perm, h1b, N);

    // --- layer 2 (GEMM + MFMA el/er) ---
    mfma_gemm_kernel<false, true, false, true><<<ggrid, 256, 0, stream>>>(
        h1b, WT2, nullptr, ALR2, featb, el, er, N);
    aggregate_head_kernel<true><<<agrid, 256, 0, stream>>>(
        featb, el, er, b2, offs, csrsrc, perm, h_out, N);

    // --- projection (reads fp32 h_out, converts to bf16 in-register) ---
    mfma_gemm_kernel<true, false, true, false><<<ggrid, 256, 0, stream>>>(
        h_out, WTp, bp, nullptr, p_out, nullptr, nullptr, N);
}

// Round 13
// 246.320 us; speedup vs baseline: 1.3607x; 1.3607x over previous
//
#include <hip/hip_runtime.h>
#include <hip/hip_bf16.h>

#define N_NODES 50000
#define HEADS 4
#define DHEAD 32
#define F 128           // HEADS*DHEAD = in/out feature width everywhere
#define NEG_SLOPE 0.2f
#define MAXD 64         // LDS-stash fast-path degree bound

typedef unsigned int uint;
typedef unsigned short ushort;
typedef __attribute__((ext_vector_type(8))) short bf16x8;
typedef __attribute__((ext_vector_type(4))) float f32x4;

__device__ __forceinline__ float bf2f(ushort u) {
    union { uint i; float f; } c; c.i = ((uint)u) << 16; return c.f;
}
__device__ __forceinline__ ushort f2bf(float f) {
    union { float f; uint i; } c; c.f = f;
    uint u = c.i + 0x7FFF + ((c.i >> 16) & 1);   // round-to-nearest-even
    return (ushort)(u >> 16);
}
__device__ __forceinline__ float sel4(int h, float a, float b, float c, float d) {
    return (h & 2) ? ((h & 1) ? d : c) : ((h & 1) ? b : a);
}

// ---------------------------------------------------------------------------
// CSR build: rank+hist -> hierarchical scan -> posfix -> range-split scatter
// ---------------------------------------------------------------------------
__global__ void rank_hist_kernel(const int* __restrict__ dst, int* __restrict__ counts,
                                 int* __restrict__ rank, int E) {
    int i = blockIdx.x * 256 + threadIdx.x;
    if (i < E) rank[i] = atomicAdd(&counts[dst[i]], 1);
}

__global__ __launch_bounds__(256) void scanA_kernel(const int* __restrict__ counts,
                                                    int* __restrict__ local_sc,
                                                    int* __restrict__ partials, int N) {
    int i = blockIdx.x * 256 + threadIdx.x;
    int v = (i < N) ? counts[i] : 0;
    int lane = threadIdx.x & 63;
    int w = threadIdx.x >> 6;
    int x = v;
#pragma unroll
    for (int off = 1; off < 64; off <<= 1) {
        int t = __shfl_up(x, off);
        if (lane >= off) x += t;
    }
    __shared__ int wsum[4];
    if (lane == 63) wsum[w] = x;
    __syncthreads();
    int wpre = 0;
#pragma unroll
    for (int k = 0; k < 4; k++)
        if (k < w) wpre += wsum[k];
    if (i < N) local_sc[i] = x - v + wpre;
    if (threadIdx.x == 255) partials[blockIdx.x] = wpre + x;
}

__global__ void scanB_kernel(int* __restrict__ partials, int NP) {
    int tid = threadIdx.x;
    int v = (tid < NP) ? partials[tid] : 0;
    int lane = tid & 63;
    int w = tid >> 6;
    int x = v;
#pragma unroll
    for (int off = 1; off < 64; off <<= 1) {
        int t = __shfl_up(x, off);
        if (lane >= off) x += t;
    }
    __shared__ int wsum[4];
    if (lane == 63) wsum[w] = x;
    __syncthreads();
    int wpre = 0;
#pragma unroll
    for (int k = 0; k < 4; k++)
        if (k < w) wpre += wsum[k];
    if (tid < NP) partials[tid] = x - v + wpre;
}

__global__ __launch_bounds__(256) void scanC_kernel(int* __restrict__ offs,
                                                    const int* __restrict__ partials,
                                                    int N, int E) {
    int i = blockIdx.x * 256 + threadIdx.x;
    if (i < N) offs[i] += partials[blockIdx.x];
    if (i == 0) offs[N] = E;
}

__global__ void posfix_kernel(const int* __restrict__ dst, const int* __restrict__ offs,
                              int* __restrict__ rank, int E) {
    int i = blockIdx.x * 256 + threadIdx.x;
    if (i < E) rank[i] += offs[dst[i]];
}

#define SCH 2048   // edges per block chunk
__global__ __launch_bounds__(256) void scatter_ranged_kernel(
    const int* __restrict__ src, const int* __restrict__ pos,
    int* __restrict__ csr_src, int E) {
    int range = blockIdx.x & 7;
    int chunk = blockIdx.x >> 3;
    int base = chunk * SCH + threadIdx.x;
    int lo = (int)(((long long)range * E) >> 3);
    int hi = (int)(((long long)(range + 1) * E) >> 3);
#pragma unroll
    for (int k = 0; k < SCH / 256; k++) {
        int i = base + k * 256;
        if (i < E) {
            int p = pos[i];
            if (p >= lo && p < hi) csr_src[p] = src[i];
        }
    }
}

// ---------------------------------------------------------------------------
// Weight transpose + bf16 convert. Blocks 0-2: WT[n][k]=bf16(W[k][n]).
// Blocks 3-4: W-PROJECTED ALR tables (16x128):
//   ALR[c][k] = sum_d W[k][h*32+d] * a[h][d],  h=c&3, a=al (c<4) / ar (4..7).
// ---------------------------------------------------------------------------
__global__ __launch_bounds__(256) void wtrans_kernel(
    const float* __restrict__ W1, const float* __restrict__ W2,
    const float* __restrict__ Wp,
    const float* __restrict__ al1, const float* __restrict__ ar1,
    const float* __restrict__ al2, const float* __restrict__ ar2,
    ushort* __restrict__ WT) {
    if (blockIdx.x < 3) {
        const float* W = (blockIdx.x == 0) ? W1 : (blockIdx.x == 1) ? W2 : Wp;
        ushort* T = WT + (size_t)blockIdx.x * 128 * 128;
        for (int i = threadIdx.x; i < 128 * 128; i += 256) {
            int r = i >> 7, c = i & 127;
            T[c * 128 + r] = f2bf(W[i]);
        }
    } else {
        const float* W   = (blockIdx.x == 3) ? W1 : W2;
        const float* a_l = (blockIdx.x == 3) ? al1 : al2;
        const float* a_r = (blockIdx.x == 3) ? ar1 : ar2;
        ushort* T = WT + 3 * 128 * 128 + (blockIdx.x - 3) * 16 * 128;
        for (int i = threadIdx.x; i < 16 * 128; i += 256) {
            int c = i >> 7, k = i & 127;
            float v = 0.f;
            if (c < 8) {
                int h = c & 3;
                const float* a  = (c < 4) ? (a_l + h * 32) : (a_r + h * 32);
                const float* wr = W + k * 128 + h * 32;
#pragma unroll
                for (int d = 0; d < 32; d++) v += wr[d] * a[d];
            }
            T[i] = f2bf(v);
        }
    }
}

// ---------------------------------------------------------------------------
// MFMA GEMM: C[M,128] = A[M,128] @ B[128,128], B transposed bf16 (BT[n][k]).
// Block = 4 waves, each wave 16 rows x 128 cols.
// ELER: one extra 16x16x32 MFMA chain vs the W-projected ALR table computes
// el (cols 0-3) and er (cols 4-7) for the wave's 16 rows.
// ---------------------------------------------------------------------------
template <bool A_FP32, bool OUT_BF16, bool BIAS, bool ELER>
__global__ __launch_bounds__(256) void mfma_gemm_kernel(
    const void* __restrict__ Av, const ushort* __restrict__ BT,
    const float* __restrict__ bias, const ushort* __restrict__ ALR,
    void* __restrict__ Cv, float* __restrict__ el, float* __restrict__ er, int M) {
    int wid = threadIdx.x >> 6;
    int lane = threadIdx.x & 63;
    int row0 = blockIdx.x * 64 + wid * 16;
    int rsub = lane & 15;
    int kg = lane >> 4;
    int row = row0 + rsub;
    int rowc = (row < M) ? row : (M - 1);

    bf16x8 af[4];
    if (A_FP32) {
        const float* A = (const float*)Av;
        const float* ap = A + (size_t)rowc * 128 + kg * 8;
#pragma unroll
        for (int ks = 0; ks < 4; ks++) {
            float4 lo = *(const float4*)(ap + ks * 32);
            float4 hi = *(const float4*)(ap + ks * 32 + 4);
            bf16x8 v;
            v[0] = (short)f2bf(lo.x); v[1] = (short)f2bf(lo.y);
            v[2] = (short)f2bf(lo.z); v[3] = (short)f2bf(lo.w);
            v[4] = (short)f2bf(hi.x); v[5] = (short)f2bf(hi.y);
            v[6] = (short)f2bf(hi.z); v[7] = (short)f2bf(hi.w);
            af[ks] = v;
        }
    } else {
        const ushort* A = (const ushort*)Av;
        const ushort* ap = A + (size_t)rowc * 128 + kg * 8;
#pragma unroll
        for (int ks = 0; ks < 4; ks++) af[ks] = *(const bf16x8*)(ap + ks * 32);
    }

    f32x4 acc[8];
#pragma unroll
    for (int ct = 0; ct < 8; ct++) acc[ct] = (f32x4){0.f, 0.f, 0.f, 0.f};

    const ushort* bp = BT + (size_t)rsub * 128 + kg * 8;
#pragma unroll
    for (int ks = 0; ks < 4; ks++) {
#pragma unroll
        for (int ct = 0; ct < 8; ct++) {
            bf16x8 bf = *(const bf16x8*)(bp + (size_t)ct * 16 * 128 + ks * 32);
            acc[ct] = __builtin_amdgcn_mfma_f32_16x16x32_bf16(af[ks], bf, acc[ct], 0, 0, 0);
        }
    }

    f32x4 acce = (f32x4){0.f, 0.f, 0.f, 0.f};
    if (ELER) {
        const ushort* ep = ALR + rsub * 128 + kg * 8;
#pragma unroll
        for (int ks = 0; ks < 4; ks++) {
            bf16x8 eb = *(const bf16x8*)(ep + ks * 32);
            acce = __builtin_amdgcn_mfma_f32_16x16x32_bf16(af[ks], eb, acce, 0, 0, 0);
        }
    }

    if (row0 >= M) return;

#pragma unroll
    for (int ct = 0; ct < 8; ct++) {
        int col = ct * 16 + rsub;
        float bv = BIAS ? bias[col] : 0.f;
#pragma unroll
        for (int r = 0; r < 4; r++) {
            int gr = row0 + kg * 4 + r;
            if (gr < M) {
                float v = acc[ct][r] + bv;
                if (OUT_BF16) ((ushort*)Cv)[(size_t)gr * 128 + col] = f2bf(v);
                else          ((float*)Cv)[(size_t)gr * 128 + col] = v;
            }
        }
    }

    if (ELER && rsub < 8) {
#pragma unroll
        for (int r = 0; r < 4; r++) {
            int gr = row0 + kg * 4 + r;
            if (gr < M) {
                if (rsub < 4) el[(size_t)gr * 4 + rsub] = acce[r];
                else          er[(size_t)gr * 4 + (rsub - 4)] = acce[r];
            }
        }
    }
}

// ---------------------------------------------------------------------------
// Aggregate: 16 lanes per node (4 nodes/wave, 16 nodes/block). Fast path
// (deg<=64): pass1 stashes (sv, leaky-logit[4]) in LDS while doing online
// softmax; pass2 per edge reads sv+logit from LDS, one exp, one 16B feat
// gather, 8 fma — no random el/csr re-loads, no shfls. Slow path (deg>64):
// R6-style 4-edge shfl batches.
// ---------------------------------------------------------------------------
template <bool F32OUT>
__global__ __launch_bounds__(256) void aggregate_kernel(
    const ushort* __restrict__ featb, const float* __restrict__ el,
    const float* __restrict__ er, const float* __restrict__ bias,
    const int* __restrict__ offsets, const int* __restrict__ csr_src,
    void* __restrict__ outv, int N) {
    __shared__ int   s_sv[16][MAXD + 1];        // +1 pad: group stride 65
    __shared__ float s_lg[16][MAXD + 1][4];
    int tid = threadIdx.x;
    int gl = tid & 15;
    int g  = tid >> 4;
    int lane = tid & 63;
    int n = blockIdx.x * 16 + g;
    if (n >= N) return;
    int start = offsets[n], end = offsets[n + 1];
    int deg = end - start;
    bool fast = (deg <= MAXD);

    float4 erv = *(const float4*)(er + (size_t)n * 4);
    float er_h[4] = {erv.x, erv.y, erv.z, erv.w};

    float m[4], s[4];
#pragma unroll
    for (int h = 0; h < 4; h++) { m[h] = -1e30f; s[h] = 0.f; }

    // pass 1: logits + online softmax (stash to LDS on fast path)
    for (int e = start + gl; e < end; e += 16) {
        int sv = csr_src[e];
        float4 ev = *(const float4*)(el + (size_t)sv * 4);
        float elh[4] = {ev.x, ev.y, ev.z, ev.w};
        int idx = e - start;
        if (fast) s_sv[g][idx] = sv;
#pragma unroll
        for (int h = 0; h < 4; h++) {
            float v = elh[h] + er_h[h];
            v = (v >= 0.f) ? v : NEG_SLOPE * v;
            if (fast) s_lg[g][idx][h] = v;
            float mn = fmaxf(m[h], v);
            s[h] = s[h] * __expf(m[h] - mn) + __expf(v - mn);
            m[h] = mn;
        }
    }
#pragma unroll
    for (int off = 1; off < 16; off <<= 1) {
#pragma unroll
        for (int h = 0; h < 4; h++) {
            float mo = __shfl_xor(m[h], off);
            float so = __shfl_xor(s[h], off);
            float mn = fmaxf(m[h], mo);
            s[h] = s[h] * __expf(m[h] - mn) + so * __expf(mo - mn);
            m[h] = mn;
        }
    }

    int h0 = gl >> 2;
    int c0 = gl * 8;
    float mh  = sel4(h0, m[0], m[1], m[2], m[3]);
    float sh  = sel4(h0, s[0], s[1], s[2], s[3]);
    float rzh = (deg > 0) ? 1.0f / sh : 0.f;

    float acc[8] = {};
    if (fast) {
        for (int e0 = 0; e0 < deg; e0 += 4) {
            int nb = deg - e0; if (nb > 4) nb = 4;
#pragma unroll
            for (int jj = 0; jj < 4; jj++) {
                if (jj < nb) {
                    int sv = s_sv[g][e0 + jj];
                    float lg = s_lg[g][e0 + jj][h0];
                    float a = __expf(lg - mh) * rzh;
                    uint4 f0 = *(const uint4*)(featb + (size_t)sv * 128 + c0);
                    acc[0] = fmaf(a, bf2f(f0.x & 0xFFFF), acc[0]);
                    acc[1] = fmaf(a, bf2f(f0.x >> 16),    acc[1]);
                    acc[2] = fmaf(a, bf2f(f0.y & 0xFFFF), acc[2]);
                    acc[3] = fmaf(a, bf2f(f0.y >> 16),    acc[3]);
                    acc[4] = fmaf(a, bf2f(f0.z & 0xFFFF), acc[4]);
                    acc[5] = fmaf(a, bf2f(f0.z >> 16),    acc[5]);
                    acc[6] = fmaf(a, bf2f(f0.w & 0xFFFF), acc[6]);
                    acc[7] = fmaf(a, bf2f(f0.w >> 16),    acc[7]);
                }
            }
        }
    } else {
        int j = gl & 3;
        float erh = sel4(h0, er_h[0], er_h[1], er_h[2], er_h[3]);
        int bidx = lane & 60;
        for (int e = start; e < end; e += 4) {
            int rem = end - e;
            int ej = e + ((j < rem) ? j : 0);
            int svj = csr_src[ej];
            float v = el[(size_t)svj * 4 + h0] + erh;
            v = (v >= 0.f) ? v : NEG_SLOPE * v;
            float a = __expf(v - mh) * rzh;
            if (j >= rem) a = 0.f;
#pragma unroll
            for (int jj = 0; jj < 4; jj++) {
                float ajj = __shfl(a, bidx | jj);
                int svjj  = __shfl(svj, bidx | jj);
                uint4 f0 = *(const uint4*)(featb + (size_t)svjj * 128 + c0);
                acc[0] = fmaf(ajj, bf2f(f0.x & 0xFFFF), acc[0]);
                acc[1] = fmaf(ajj, bf2f(f0.x >> 16),    acc[1]);
                acc[2] = fmaf(ajj, bf2f(f0.y & 0xFFFF), acc[2]);
                acc[3] = fmaf(ajj, bf2f(f0.y >> 16),    acc[3]);
                acc[4] = fmaf(ajj, bf2f(f0.z & 0xFFFF), acc[4]);
                acc[5] = fmaf(ajj, bf2f(f0.z >> 16),    acc[5]);
                acc[6] = fmaf(ajj, bf2f(f0.w & 0xFFFF), acc[6]);
                acc[7] = fmaf(ajj, bf2f(f0.w >> 16),    acc[7]);
            }
        }
    }

    float4 b0 = *(const float4*)(bias + c0);
    float4 b1 = *(const float4*)(bias + c0 + 4);
    float o[8];
    o[0] = acc[0] + b0.x; o[1] = acc[1] + b0.y; o[2] = acc[2] + b0.z; o[3] = acc[3] + b0.w;
    o[4] = acc[4] + b1.x; o[5] = acc[5] + b1.y; o[6] = acc[6] + b1.z; o[7] = acc[7] + b1.w;
    if (F32OUT) {
        float* outf = (float*)outv;
        float4 w0, w1;
        w0.x = o[0]; w0.y = o[1]; w0.z = o[2]; w0.w = o[3];
        w1.x = o[4]; w1.y = o[5]; w1.z = o[6]; w1.w = o[7];
        *(float4*)(outf + (size_t)n * 128 + c0) = w0;
        *(float4*)(outf + (size_t)n * 128 + c0 + 4) = w1;
    } else {
        ushort* outb = (ushort*)outv;
        uint4 p;
        p.x = (uint)f2bf(o[0]) | ((uint)f2bf(o[1]) << 16);
        p.y = (uint)f2bf(o[2]) | ((uint)f2bf(o[3]) << 16);
        p.z = (uint)f2bf(o[4]) | ((uint)f2bf(o[5]) << 16);
        p.w = (uint)f2bf(o[6]) | ((uint)f2bf(o[7]) << 16);
        *(uint4*)(outb + (size_t)n * 128 + c0) = p;
    }
}

// ---------------------------------------------------------------------------
extern "C" void kernel_launch(void* const* d_in, const int* in_sizes, int n_in,
                              void* d_out, int out_size, void* d_ws, size_t ws_size,
                              hipStream_t stream) {
    const float* x   = (const float*)d_in[0];
    const int*   src = (const int*)d_in[1];
    const int*   dst = (const int*)d_in[2];
    const float* W1  = (const float*)d_in[3];
    const float* al1 = (const float*)d_in[4];
    const float* ar1 = (const float*)d_in[5];
    const float* b1  = (const float*)d_in[6];
    const float* W2  = (const float*)d_in[7];
    const float* al2 = (const float*)d_in[8];
    const float* ar2 = (const float*)d_in[9];
    const float* b2  = (const float*)d_in[10];
    const float* Wp  = (const float*)d_in[11];
    const float* bp  = (const float*)d_in[12];

    const int N = in_sizes[0] / F;      // 50000
    const int E = in_sizes[1];          // 800000

    float* h_out = (float*)d_out;               // [N,128]  (layer-2 output h, checked)
    float* p_out = h_out + (size_t)N * F;       // [N,128]  (projection output, checked)

    const int NB = (N + 255) / 256;
    const int EB = (E + 255) / 256;

    // workspace carve
    char* w = (char*)d_ws;
    ushort* featb   = (ushort*)w;                               // N*128 bf16
    ushort* h1b     = featb + (size_t)N * F;                    // N*128 bf16
    float* el       = (float*)(h1b + (size_t)N * F);            // N*4
    float* er       = el + (size_t)N * 4;                       // N*4
    int*   offs     = (int*)(er + (size_t)N * 4);               // N+1
    int*   counts   = offs + (N + 1);                           // N
    int*   rank     = counts + N;                               // E (becomes pos)
    int*   csrsrc   = rank + E;                                 // E
    int*   partials = csrsrc + E;                               // 256
    ushort* WT      = (ushort*)(partials + 256);                // 3*16384 + 2*2048

    // --- CSR build (dst is identical for both layers) ---
    hipMemsetAsync(counts, 0, (size_t)N * 4, stream);
    rank_hist_kernel<<<EB, 256, 0, stream>>>(dst, counts, rank, E);
    scanA_kernel<<<NB, 256, 0, stream>>>(counts, offs, partials, N);
    scanB_kernel<<<1, 256, 0, stream>>>(partials, NB);
    scanC_kernel<<<NB, 256, 0, stream>>>(offs, partials, N, E);
    posfix_kernel<<<EB, 256, 0, stream>>>(dst, offs, rank, E);
    scatter_ranged_kernel<<<8 * ((E + SCH - 1) / SCH), 256, 0, stream>>>(src, rank, csrsrc, E);

    // --- weight transposes + W-projected ALR tables (bf16) ---
    wtrans_kernel<<<5, 256, 0, stream>>>(W1, W2, Wp, al1, ar1, al2, ar2, WT);
    ushort* WT1  = WT;
    ushort* WT2  = WT + 128 * 128;
    ushort* WTp  = WT + 2 * 128 * 128;
    ushort* ALR1 = WT + 3 * 128 * 128;
    ushort* ALR2 = ALR1 + 16 * 128;

    int ggrid = (N + 63) / 64;
    int agrid = (N + 15) / 16;

    // --- layer 1 (GEMM + MFMA el/er) ---
    mfma_gemm_kernel<true, true, false, true><<<ggrid, 256, 0, stream>>>(
        x, WT1, nullptr, ALR1, featb, el, er, N);
    aggregate_kernel<false><<<agrid, 256, 0, stream>>>(
        featb, el, er, b1, offs, csrsrc, h1b, N);

    // --- layer 2 (GEMM + MFMA el/er) ---
    mfma_gemm_kernel<false, true, false, true><<<ggrid, 256, 0, stream>>>(
        h1b, WT2, nullptr, ALR2, featb, el, er, N);
    aggregate_kernel<true><<<agrid, 256, 0, stream>>>(
        featb, el, er, b2, offs, csrsrc, h_out, N);

    // --- projection (reads fp32 h_out, converts to bf16 in-register) ---
    mfma_gemm_kernel<true, false, true, false><<<ggrid, 256, 0, stream>>>(
        h_out, WTp, bp, nullptr, p_out, nullptr, nullptr, N);
}

// Round 15
// 239.381 us; speedup vs baseline: 1.4001x; 1.0290x over previous
//
#include <hip/hip_runtime.h>
#include <hip/hip_bf16.h>

#define N_NODES 50000
#define HEADS 4
#define DHEAD 32
#define F 128           // HEADS*DHEAD = in/out feature width everywhere
#define NEG_SLOPE 0.2f
#define MAXD 64         // LDS-stash fast-path degree bound

typedef unsigned int uint;
typedef unsigned short ushort;
typedef __attribute__((ext_vector_type(8))) short bf16x8;
typedef __attribute__((ext_vector_type(4))) float f32x4;

__device__ __forceinline__ float bf2f(ushort u) {
    union { uint i; float f; } c; c.i = ((uint)u) << 16; return c.f;
}
__device__ __forceinline__ ushort f2bf(float f) {
    union { float f; uint i; } c; c.f = f;
    uint u = c.i + 0x7FFF + ((c.i >> 16) & 1);   // round-to-nearest-even
    return (ushort)(u >> 16);
}
__device__ __forceinline__ float sel4(int h, float a, float b, float c, float d) {
    return (h & 2) ? ((h & 1) ? d : c) : ((h & 1) ? b : a);
}

// ---------------------------------------------------------------------------
// CSR build: rank+hist (+ fused weight prep) -> scan -> posfix -> scatter
// ---------------------------------------------------------------------------
// blocks < EB: rank[i] = atomicAdd(counts[dst[i]],1).
// blocks EB..EB+2: WT[n][k] = bf16(W[k][n]) transposes.
// blocks EB+3..EB+4: W-projected ALR tables:
//   ALR[c][k] = sum_d W[k][h*32+d]*a[h][d], h=c&3, a=al(c<4)/ar(4..7).
__global__ void rank_hist_wtrans_kernel(
    const int* __restrict__ dst, int* __restrict__ counts, int* __restrict__ rank,
    const float* __restrict__ W1, const float* __restrict__ W2,
    const float* __restrict__ Wp,
    const float* __restrict__ al1, const float* __restrict__ ar1,
    const float* __restrict__ al2, const float* __restrict__ ar2,
    ushort* __restrict__ WT, int E, int EB) {
    if (blockIdx.x < (uint)EB) {
        int i = blockIdx.x * 256 + threadIdx.x;
        if (i < E) rank[i] = atomicAdd(&counts[dst[i]], 1);
        return;
    }
    int bid = blockIdx.x - EB;
    if (bid < 3) {
        const float* W = (bid == 0) ? W1 : (bid == 1) ? W2 : Wp;
        ushort* T = WT + (size_t)bid * 128 * 128;
        for (int i = threadIdx.x; i < 128 * 128; i += 256) {
            int r = i >> 7, c = i & 127;
            T[c * 128 + r] = f2bf(W[i]);
        }
    } else {
        const float* W   = (bid == 3) ? W1 : W2;
        const float* a_l = (bid == 3) ? al1 : al2;
        const float* a_r = (bid == 3) ? ar1 : ar2;
        ushort* T = WT + 3 * 128 * 128 + (bid - 3) * 16 * 128;
        for (int i = threadIdx.x; i < 16 * 128; i += 256) {
            int c = i >> 7, k = i & 127;
            float v = 0.f;
            if (c < 8) {
                int h = c & 3;
                const float* a  = (c < 4) ? (a_l + h * 32) : (a_r + h * 32);
                const float* wr = W + k * 128 + h * 32;
#pragma unroll
                for (int d = 0; d < 32; d++) v += wr[d] * a[d];
            }
            T[i] = f2bf(v);
        }
    }
}

__global__ __launch_bounds__(256) void scanA_kernel(const int* __restrict__ counts,
                                                    int* __restrict__ local_sc,
                                                    int* __restrict__ partials, int N) {
    int i = blockIdx.x * 256 + threadIdx.x;
    int v = (i < N) ? counts[i] : 0;
    int lane = threadIdx.x & 63;
    int w = threadIdx.x >> 6;
    int x = v;
#pragma unroll
    for (int off = 1; off < 64; off <<= 1) {
        int t = __shfl_up(x, off);
        if (lane >= off) x += t;
    }
    __shared__ int wsum[4];
    if (lane == 63) wsum[w] = x;
    __syncthreads();
    int wpre = 0;
#pragma unroll
    for (int k = 0; k < 4; k++)
        if (k < w) wpre += wsum[k];
    if (i < N) local_sc[i] = x - v + wpre;
    if (threadIdx.x == 255) partials[blockIdx.x] = wpre + x;
}

__global__ void scanB_kernel(int* __restrict__ partials, int NP) {
    int tid = threadIdx.x;
    int v = (tid < NP) ? partials[tid] : 0;
    int lane = tid & 63;
    int w = tid >> 6;
    int x = v;
#pragma unroll
    for (int off = 1; off < 64; off <<= 1) {
        int t = __shfl_up(x, off);
        if (lane >= off) x += t;
    }
    __shared__ int wsum[4];
    if (lane == 63) wsum[w] = x;
    __syncthreads();
    int wpre = 0;
#pragma unroll
    for (int k = 0; k < 4; k++)
        if (k < w) wpre += wsum[k];
    if (tid < NP) partials[tid] = x - v + wpre;
}

__global__ __launch_bounds__(256) void scanC_kernel(int* __restrict__ offs,
                                                    const int* __restrict__ partials,
                                                    int N, int E) {
    int i = blockIdx.x * 256 + threadIdx.x;
    if (i < N) offs[i] += partials[blockIdx.x];
    if (i == 0) offs[N] = E;
}

__global__ void posfix_kernel(const int* __restrict__ dst, const int* __restrict__ offs,
                              int* __restrict__ rank, int E) {
    int i = blockIdx.x * 256 + threadIdx.x;
    if (i < E) rank[i] += offs[dst[i]];
}

#define SCH 2048   // edges per block chunk
__global__ __launch_bounds__(256) void scatter_ranged_kernel(
    const int* __restrict__ src, const int* __restrict__ pos,
    int* __restrict__ csr_src, int E) {
    int range = blockIdx.x & 7;
    int chunk = blockIdx.x >> 3;
    int base = chunk * SCH + threadIdx.x;
    int lo = (int)(((long long)range * E) >> 3);
    int hi = (int)(((long long)(range + 1) * E) >> 3);
#pragma unroll
    for (int k = 0; k < SCH / 256; k++) {
        int i = base + k * 256;
        if (i < E) {
            int p = pos[i];
            if (p >= lo && p < hi) csr_src[p] = src[i];
        }
    }
}

// ---------------------------------------------------------------------------
// MFMA GEMM: C[M,128] = A[M,128] @ B[128,128], B transposed bf16 (BT[n][k]).
// Block = 4 waves, each wave 16 rows x 128 cols.
// ELER: one extra 16x16x32 MFMA chain vs the W-projected ALR table computes
// el (cols 0-3) and er (cols 4-7) for the wave's 16 rows.
// ---------------------------------------------------------------------------
template <bool A_FP32, bool OUT_BF16, bool BIAS, bool ELER>
__global__ __launch_bounds__(256) void mfma_gemm_kernel(
    const void* __restrict__ Av, const ushort* __restrict__ BT,
    const float* __restrict__ bias, const ushort* __restrict__ ALR,
    void* __restrict__ Cv, float* __restrict__ el, float* __restrict__ er, int M) {
    int wid = threadIdx.x >> 6;
    int lane = threadIdx.x & 63;
    int row0 = blockIdx.x * 64 + wid * 16;
    int rsub = lane & 15;
    int kg = lane >> 4;
    int row = row0 + rsub;
    int rowc = (row < M) ? row : (M - 1);

    bf16x8 af[4];
    if (A_FP32) {
        const float* A = (const float*)Av;
        const float* ap = A + (size_t)rowc * 128 + kg * 8;
#pragma unroll
        for (int ks = 0; ks < 4; ks++) {
            float4 lo = *(const float4*)(ap + ks * 32);
            float4 hi = *(const float4*)(ap + ks * 32 + 4);
            bf16x8 v;
            v[0] = (short)f2bf(lo.x); v[1] = (short)f2bf(lo.y);
            v[2] = (short)f2bf(lo.z); v[3] = (short)f2bf(lo.w);
            v[4] = (short)f2bf(hi.x); v[5] = (short)f2bf(hi.y);
            v[6] = (short)f2bf(hi.z); v[7] = (short)f2bf(hi.w);
            af[ks] = v;
        }
    } else {
        const ushort* A = (const ushort*)Av;
        const ushort* ap = A + (size_t)rowc * 128 + kg * 8;
#pragma unroll
        for (int ks = 0; ks < 4; ks++) af[ks] = *(const bf16x8*)(ap + ks * 32);
    }

    f32x4 acc[8];
#pragma unroll
    for (int ct = 0; ct < 8; ct++) acc[ct] = (f32x4){0.f, 0.f, 0.f, 0.f};

    const ushort* bp = BT + (size_t)rsub * 128 + kg * 8;
#pragma unroll
    for (int ks = 0; ks < 4; ks++) {
#pragma unroll
        for (int ct = 0; ct < 8; ct++) {
            bf16x8 bf = *(const bf16x8*)(bp + (size_t)ct * 16 * 128 + ks * 32);
            acc[ct] = __builtin_amdgcn_mfma_f32_16x16x32_bf16(af[ks], bf, acc[ct], 0, 0, 0);
        }
    }

    f32x4 acce = (f32x4){0.f, 0.f, 0.f, 0.f};
    if (ELER) {
        const ushort* ep = ALR + rsub * 128 + kg * 8;
#pragma unroll
        for (int ks = 0; ks < 4; ks++) {
            bf16x8 eb = *(const bf16x8*)(ep + ks * 32);
            acce = __builtin_amdgcn_mfma_f32_16x16x32_bf16(af[ks], eb, acce, 0, 0, 0);
        }
    }

    if (row0 >= M) return;

#pragma unroll
    for (int ct = 0; ct < 8; ct++) {
        int col = ct * 16 + rsub;
        float bv = BIAS ? bias[col] : 0.f;
#pragma unroll
        for (int r = 0; r < 4; r++) {
            int gr = row0 + kg * 4 + r;
            if (gr < M) {
                float v = acc[ct][r] + bv;
                if (OUT_BF16) ((ushort*)Cv)[(size_t)gr * 128 + col] = f2bf(v);
                else          ((float*)Cv)[(size_t)gr * 128 + col] = v;
            }
        }
    }

    if (ELER && rsub < 8) {
#pragma unroll
        for (int r = 0; r < 4; r++) {
            int gr = row0 + kg * 4 + r;
            if (gr < M) {
                if (rsub < 4) el[(size_t)gr * 4 + rsub] = acce[r];
                else          er[(size_t)gr * 4 + (rsub - 4)] = acce[r];
            }
        }
    }
}

// ---------------------------------------------------------------------------
// Aggregate: 16 lanes per node (4 nodes/wave, 16 nodes/block). Fast path
// (deg<=64): pass1 stashes (sv, leaky-logit[4]) in LDS during the online
// softmax; after the reduce each lane converts its stashed logits to FINAL
// ALPHAS in LDS (wave-synchronous within the 16-lane group, no barrier).
// Pass2: 8-edge batches — read alpha from LDS (4-lane broadcast) + 8
// independent 16B feat gathers + 64 fma; no exp/sel in the loop.
// Slow path (deg>64): 4-edge shfl batches.
// ---------------------------------------------------------------------------
template <bool F32OUT>
__global__ __launch_bounds__(256) void aggregate_kernel(
    const ushort* __restrict__ featb, const float* __restrict__ el,
    const float* __restrict__ er, const float* __restrict__ bias,
    const int* __restrict__ offsets, const int* __restrict__ csr_src,
    void* __restrict__ outv, int N) {
    __shared__ int   s_sv[16][MAXD + 1];        // +1 pad: group stride 65
    __shared__ float s_lg[16][MAXD + 1][4];
    int tid = threadIdx.x;
    int gl = tid & 15;
    int g  = tid >> 4;
    int lane = tid & 63;
    int n = blockIdx.x * 16 + g;
    if (n >= N) return;
    int start = offsets[n], end = offsets[n + 1];
    int deg = end - start;
    bool fast = (deg <= MAXD);

    float4 erv = *(const float4*)(er + (size_t)n * 4);
    float er_h[4] = {erv.x, erv.y, erv.z, erv.w};

    float m[4], s[4];
#pragma unroll
    for (int h = 0; h < 4; h++) { m[h] = -1e30f; s[h] = 0.f; }

    // pass 1: logits + online softmax (stash to LDS on fast path)
    for (int e = start + gl; e < end; e += 16) {
        int sv = csr_src[e];
        float4 ev = *(const float4*)(el + (size_t)sv * 4);
        float elh[4] = {ev.x, ev.y, ev.z, ev.w};
        int idx = e - start;
        if (fast) s_sv[g][idx] = sv;
#pragma unroll
        for (int h = 0; h < 4; h++) {
            float v = elh[h] + er_h[h];
            v = (v >= 0.f) ? v : NEG_SLOPE * v;
            if (fast) s_lg[g][idx][h] = v;
            float mn = fmaxf(m[h], v);
            s[h] = s[h] * __expf(m[h] - mn) + __expf(v - mn);
            m[h] = mn;
        }
    }
#pragma unroll
    for (int off = 1; off < 16; off <<= 1) {
#pragma unroll
        for (int h = 0; h < 4; h++) {
            float mo = __shfl_xor(m[h], off);
            float so = __shfl_xor(s[h], off);
            float mn = fmaxf(m[h], mo);
            s[h] = s[h] * __expf(m[h] - mn) + so * __expf(mo - mn);
            m[h] = mn;
        }
    }

    int h0 = gl >> 2;
    int c0 = gl * 8;
    float acc[8] = {};

    if (fast) {
        float rz[4];
#pragma unroll
        for (int h = 0; h < 4; h++) rz[h] = (deg > 0) ? 1.0f / s[h] : 0.f;
        // convert stashed logits -> final alphas (wave-sync within group)
        for (int e = gl; e < deg; e += 16) {
#pragma unroll
            for (int h = 0; h < 4; h++)
                s_lg[g][e][h] = __expf(s_lg[g][e][h] - m[h]) * rz[h];
        }
        // pass 2: 8-wide gather batches, no exp in loop
        for (int e0 = 0; e0 < deg; e0 += 8) {
            int nb = deg - e0; if (nb > 8) nb = 8;
            float av[8]; int svv[8];
#pragma unroll
            for (int jj = 0; jj < 8; jj++) {
                int idx = (jj < nb) ? (e0 + jj) : e0;
                svv[jj] = s_sv[g][idx];
                av[jj] = (jj < nb) ? s_lg[g][idx][h0] : 0.f;
            }
#pragma unroll
            for (int jj = 0; jj < 8; jj++) {
                uint4 f0 = *(const uint4*)(featb + (size_t)svv[jj] * 128 + c0);
                acc[0] = fmaf(av[jj], bf2f(f0.x & 0xFFFF), acc[0]);
                acc[1] = fmaf(av[jj], bf2f(f0.x >> 16),    acc[1]);
                acc[2] = fmaf(av[jj], bf2f(f0.y & 0xFFFF), acc[2]);
                acc[3] = fmaf(av[jj], bf2f(f0.y >> 16),    acc[3]);
                acc[4] = fmaf(av[jj], bf2f(f0.z & 0xFFFF), acc[4]);
                acc[5] = fmaf(av[jj], bf2f(f0.z >> 16),    acc[5]);
                acc[6] = fmaf(av[jj], bf2f(f0.w & 0xFFFF), acc[6]);
                acc[7] = fmaf(av[jj], bf2f(f0.w >> 16),    acc[7]);
            }
        }
    } else {
        float mh  = sel4(h0, m[0], m[1], m[2], m[3]);
        float sh  = sel4(h0, s[0], s[1], s[2], s[3]);
        float rzh = (deg > 0) ? 1.0f / sh : 0.f;
        int j = gl & 3;
        float erh = sel4(h0, er_h[0], er_h[1], er_h[2], er_h[3]);
        int bidx = lane & 60;
        for (int e = start; e < end; e += 4) {
            int rem = end - e;
            int ej = e + ((j < rem) ? j : 0);
            int svj = csr_src[ej];
            float v = el[(size_t)svj * 4 + h0] + erh;
            v = (v >= 0.f) ? v : NEG_SLOPE * v;
            float a = __expf(v - mh) * rzh;
            if (j >= rem) a = 0.f;
#pragma unroll
            for (int jj = 0; jj < 4; jj++) {
                float ajj = __shfl(a, bidx | jj);
                int svjj  = __shfl(svj, bidx | jj);
                uint4 f0 = *(const uint4*)(featb + (size_t)svjj * 128 + c0);
                acc[0] = fmaf(ajj, bf2f(f0.x & 0xFFFF), acc[0]);
                acc[1] = fmaf(ajj, bf2f(f0.x >> 16),    acc[1]);
                acc[2] = fmaf(ajj, bf2f(f0.y & 0xFFFF), acc[2]);
                acc[3] = fmaf(ajj, bf2f(f0.y >> 16),    acc[3]);
                acc[4] = fmaf(ajj, bf2f(f0.z & 0xFFFF), acc[4]);
                acc[5] = fmaf(ajj, bf2f(f0.z >> 16),    acc[5]);
                acc[6] = fmaf(ajj, bf2f(f0.w & 0xFFFF), acc[6]);
                acc[7] = fmaf(ajj, bf2f(f0.w >> 16),    acc[7]);
            }
        }
    }

    float4 b0 = *(const float4*)(bias + c0);
    float4 b1 = *(const float4*)(bias + c0 + 4);
    float o[8];
    o[0] = acc[0] + b0.x; o[1] = acc[1] + b0.y; o[2] = acc[2] + b0.z; o[3] = acc[3] + b0.w;
    o[4] = acc[4] + b1.x; o[5] = acc[5] + b1.y; o[6] = acc[6] + b1.z; o[7] = acc[7] + b1.w;
    if (F32OUT) {
        float* outf = (float*)outv;
        float4 w0, w1;
        w0.x = o[0]; w0.y = o[1]; w0.z = o[2]; w0.w = o[3];
        w1.x = o[4]; w1.y = o[5]; w1.z = o[6]; w1.w = o[7];
        *(float4*)(outf + (size_t)n * 128 + c0) = w0;
        *(float4*)(outf + (size_t)n * 128 + c0 + 4) = w1;
    } else {
        ushort* outb = (ushort*)outv;
        uint4 p;
        p.x = (uint)f2bf(o[0]) | ((uint)f2bf(o[1]) << 16);
        p.y = (uint)f2bf(o[2]) | ((uint)f2bf(o[3]) << 16);
        p.z = (uint)f2bf(o[4]) | ((uint)f2bf(o[5]) << 16);
        p.w = (uint)f2bf(o[6]) | ((uint)f2bf(o[7]) << 16);
        *(uint4*)(outb + (size_t)n * 128 + c0) = p;
    }
}

// ---------------------------------------------------------------------------
extern "C" void kernel_launch(void* const* d_in, const int* in_sizes, int n_in,
                              void* d_out, int out_size, void* d_ws, size_t ws_size,
                              hipStream_t stream) {
    const float* x   = (const float*)d_in[0];
    const int*   src = (const int*)d_in[1];
    const int*   dst = (const int*)d_in[2];
    const float* W1  = (const float*)d_in[3];
    const float* al1 = (const float*)d_in[4];
    const float* ar1 = (const float*)d_in[5];
    const float* b1  = (const float*)d_in[6];
    const float* W2  = (const float*)d_in[7];
    const float* al2 = (const float*)d_in[8];
    const float* ar2 = (const float*)d_in[9];
    const float* b2  = (const float*)d_in[10];
    const float* Wp  = (const float*)d_in[11];
    const float* bp  = (const float*)d_in[12];

    const int N = in_sizes[0] / F;      // 50000
    const int E = in_sizes[1];          // 800000

    float* h_out = (float*)d_out;               // [N,128]  (layer-2 output h, checked)
    float* p_out = h_out + (size_t)N * F;       // [N,128]  (projection output, checked)

    const int NB = (N + 255) / 256;
    const int EB = (E + 255) / 256;

    // workspace carve
    char* w = (char*)d_ws;
    ushort* featb   = (ushort*)w;                               // N*128 bf16
    ushort* h1b     = featb + (size_t)N * F;                    // N*128 bf16
    float* el       = (float*)(h1b + (size_t)N * F);            // N*4
    float* er       = el + (size_t)N * 4;                       // N*4
    int*   offs     = (int*)(er + (size_t)N * 4);               // N+1
    int*   counts   = offs + (N + 1);                           // N
    int*   rank     = counts + N;                               // E (becomes pos)
    int*   csrsrc   = rank + E;                                 // E
    int*   partials = csrsrc + E;                               // 256
    ushort* WT      = (ushort*)(partials + 256);                // 3*16384 + 2*2048

    ushort* WT1  = WT;
    ushort* WT2  = WT + 128 * 128;
    ushort* WTp  = WT + 2 * 128 * 128;
    ushort* ALR1 = WT + 3 * 128 * 128;
    ushort* ALR2 = ALR1 + 16 * 128;

    // --- CSR build + weight prep (dst identical for both layers) ---
    hipMemsetAsync(counts, 0, (size_t)N * 4, stream);
    rank_hist_wtrans_kernel<<<EB + 5, 256, 0, stream>>>(
        dst, counts, rank, W1, W2, Wp, al1, ar1, al2, ar2, WT, E, EB);
    scanA_kernel<<<NB, 256, 0, stream>>>(counts, offs, partials, N);
    scanB_kernel<<<1, 256, 0, stream>>>(partials, NB);
    scanC_kernel<<<NB, 256, 0, stream>>>(offs, partials, N, E);
    posfix_kernel<<<EB, 256, 0, stream>>>(dst, offs, rank, E);
    scatter_ranged_kernel<<<8 * ((E + SCH - 1) / SCH), 256, 0, stream>>>(src, rank, csrsrc, E);

    int ggrid = (N + 63) / 64;
    int agrid = (N + 15) / 16;

    // --- layer 1 (GEMM + MFMA el/er) ---
    mfma_gemm_kernel<true, true, false, true><<<ggrid, 256, 0, stream>>>(
        x, WT1, nullptr, ALR1, featb, el, er, N);
    aggregate_kernel<false><<<agrid, 256, 0, stream>>>(
        featb, el, er, b1, offs, csrsrc, h1b, N);

    // --- layer 2 (GEMM + MFMA el/er) ---
    mfma_gemm_kernel<false, true, false, true><<<ggrid, 256, 0, stream>>>(
        h1b, WT2, nullptr, ALR2, featb, el, er, N);
    aggregate_kernel<true><<<agrid, 256, 0, stream>>>(
        featb, el, er, b2, offs, csrsrc, h_out, N);

    // --- projection (reads fp32 h_out, converts to bf16 in-register) ---
    mfma_gemm_kernel<true, false, true, false><<<ggrid, 256, 0, stream>>>(
        h_out, WTp, bp, nullptr, p_out, nullptr, nullptr, N);
}